// Round 1
// baseline (738.775 us; speedup 1.0000x reference)
//
#include <hip/hip_runtime.h>
#include <hip/hip_bf16.h>

// TemporalAttention fused kernel for MI355X (gfx950).
// One block per (b,n) sequence: 256 threads = 4 waves, each wave handles 2 heads.
// All GEMMs computed transposed (W @ X^T) so both MFMA operands are contiguous
// row-major reads. bf16 MFMA 16x16x32, f32 accumulation throughout.

namespace {

constexpr int S_LEN = 64;    // sequence length
constexpr int DM    = 256;   // model dim

typedef float f32x4 __attribute__((ext_vector_type(4)));
typedef short s16x8 __attribute__((ext_vector_type(8)));

union BF2 { __hip_bfloat162 h; unsigned u; };
__device__ __forceinline__ unsigned pkbf2(float a, float b) {
  float2 t; t.x = a; t.y = b;
  BF2 cv; cv.h = __float22bfloat162_rn(t);
  return cv.u;
}

union BF1 { __hip_bfloat16 h; unsigned short u; };
__device__ __forceinline__ unsigned short f2bf(float a) {
  BF1 cv; cv.h = __float2bfloat16(a); return cv.u;
}

// load 8 consecutive f32, convert to 8 packed bf16 (one MFMA fragment)
__device__ __forceinline__ s16x8 load_cvt8(const float* __restrict__ p) {
  f32x4 a = *(const f32x4*)p;
  f32x4 b = *(const f32x4*)(p + 4);
  union { s16x8 v; unsigned u[4]; } r;
  r.u[0] = pkbf2(a[0], a[1]); r.u[1] = pkbf2(a[2], a[3]);
  r.u[2] = pkbf2(b[0], b[1]); r.u[3] = pkbf2(b[2], b[3]);
  return r.v;
}

} // namespace

__global__ void __launch_bounds__(256, 2)
ta_fused_kernel(const float* __restrict__ x, const float* __restrict__ wqkv,
                const float* __restrict__ bqkv, const float* __restrict__ wproj,
                const float* __restrict__ bproj, float* __restrict__ out,
                int bn_total)
{
  // LDS 48KB total:
  //   per wave w: wl = lds + w*6144 : qk/pt buffer [64][64] bf16 (8KB, XOR-swizzled)
  //               vtl = wl + 4096   : vt buffer [32][64] bf16 (V transposed, 4KB)
  //   after barrier, overlapping region: att[64][256] bf16 (32KB, swizzled)
  __shared__ __align__(16) unsigned short lds[24576];

  const int bn = blockIdx.x;
  if (bn >= bn_total) return;
  const int tid = (int)threadIdx.x;
  const int w = tid >> 6;       // wave 0..3
  const int l = tid & 63;       // lane
  const int g = l >> 4;         // k-group 0..3
  const int c = l & 15;         // spatial index 0..15
  const int c7s = (c & 7) << 3; // swizzle term for rows ≡ c (mod 8)

  const float* __restrict__ xb = x + (size_t)bn * (S_LEN * DM);
  unsigned short* __restrict__ wl  = lds + w * 6144;
  unsigned short* __restrict__ vtl = wl + 4096;

  unsigned obp[2][4][2][2];  // packed bf16 attention output, [pass][mi][nd][pair]

#pragma unroll
  for (int p = 0; p < 2; ++p) {
    const int h = 4 * p + w;   // head handled by this wave this pass
    const int t0 = 2 * h;

    // ---------------- Phase A: QKV^T = Wqkv @ X^T for head h ----------------
    // e-tiles: Q {2h,2h+1}, K {16+2h,17+2h}, V {32+2h,33+2h}
    f32x4 acc[6][4];
#pragma unroll
    for (int mi = 0; mi < 6; ++mi)
#pragma unroll
      for (int nj = 0; nj < 4; ++nj) acc[mi][nj] = f32x4{0.f, 0.f, 0.f, 0.f};

#pragma unroll
    for (int ks = 0; ks < 8; ++ks) {
      const int kof = ks * 32 + g * 8;
      s16x8 bx[4];  // B-fragments = rows of X
#pragma unroll
      for (int nj = 0; nj < 4; ++nj)
        bx[nj] = load_cvt8(xb + (size_t)(16 * nj + c) * DM + kof);
#pragma unroll
      for (int mi = 0; mi < 6; ++mi) {
        const int tile = t0 + (mi & 1) + (mi >> 1) * 16;
        s16x8 aw = load_cvt8(wqkv + (size_t)(tile * 16 + c) * DM + kof);
#pragma unroll
        for (int nj = 0; nj < 4; ++nj)
          acc[mi][nj] = __builtin_amdgcn_mfma_f32_16x16x32_bf16(aw, bx[nj], acc[mi][nj], 0, 0, 0);
      }
    }

    // Epilogue: add bias, write Q,K -> qk buffer; V -> vt (transposed) buffer.
    // acc value = (e = tile*16 + 4g + r, xrow = 16nj + c)
#pragma unroll
    for (int mi = 0; mi < 6; ++mi) {
      const int tile = t0 + (mi & 1) + (mi >> 1) * 16;
      f32x4 bq = *(const f32x4*)(bqkv + tile * 16 + 4 * g);
      if (mi < 4) {
        // Q cols 0..31 (mi 0,1), K cols 32..63 (mi 2,3); 4 consecutive cols per lane
        const int colb = mi * 16 + 4 * g;
#pragma unroll
        for (int nj = 0; nj < 4; ++nj) {
          const int row = 16 * nj + c;
          unsigned u0 = pkbf2(acc[mi][nj][0] + bq[0], acc[mi][nj][1] + bq[1]);
          unsigned u1 = pkbf2(acc[mi][nj][2] + bq[2], acc[mi][nj][3] + bq[3]);
          const int idx = (row * 64 + colb) ^ c7s;   // row&7 == c&7
          *(uint2*)&wl[idx] = make_uint2(u0, u1);
        }
      } else {
#pragma unroll
        for (int nj = 0; nj < 4; ++nj) {
          const int key = 16 * nj + c;
#pragma unroll
          for (int r = 0; r < 4; ++r) {
            const int d = (mi - 4) * 16 + 4 * g + r;
            vtl[(d * 64 + key) ^ ((d & 7) << 3)] = f2bf(acc[mi][nj][r] + bq[r]);
          }
        }
      }
    }

    // ---------------- Phase B: attention for head h ----------------
    // S^T = K @ Q^T : A = K rows, B = Q rows (both contiguous in qk buffer)
    s16x8 ka[4], qa[4];
#pragma unroll
    for (int ki = 0; ki < 4; ++ki) {
      const int key = 16 * ki + c;
      ka[ki] = *(const s16x8*)&wl[(key * 64 + 32 + 8 * g) ^ c7s];
    }
#pragma unroll
    for (int qi = 0; qi < 4; ++qi) {
      const int q = 16 * qi + c;
      qa[qi] = *(const s16x8*)&wl[(q * 64 + 8 * g) ^ c7s];
    }
    f32x4 sa[4][4];  // [ki][qi]: value at (key=16ki+4g+r, q=16qi+c)
#pragma unroll
    for (int ki = 0; ki < 4; ++ki)
#pragma unroll
      for (int qi = 0; qi < 4; ++qi) {
        f32x4 z = f32x4{0.f, 0.f, 0.f, 0.f};
        sa[ki][qi] = __builtin_amdgcn_mfma_f32_16x16x32_bf16(ka[ki], qa[qi], z, 0, 0, 0);
      }

    // softmax over keys (in-lane 16 values + butterfly across 4 lane-groups)
    const float sc = 0.17677669529663687f * 1.4426950408889634f; // scale*log2(e)
    float inv[4];
#pragma unroll
    for (int qi = 0; qi < 4; ++qi) {
      float m = sa[0][qi][0];
#pragma unroll
      for (int ki = 0; ki < 4; ++ki)
#pragma unroll
        for (int r = 0; r < 4; ++r) m = fmaxf(m, sa[ki][qi][r]);
      m = fmaxf(m, __shfl_xor(m, 16));
      m = fmaxf(m, __shfl_xor(m, 32));
      float s = 0.0f;
#pragma unroll
      for (int ki = 0; ki < 4; ++ki)
#pragma unroll
        for (int r = 0; r < 4; ++r) {
          float pv = exp2f((sa[ki][qi][r] - m) * sc);
          sa[ki][qi][r] = pv;
          s += pv;
        }
      s += __shfl_xor(s, 16);
      s += __shfl_xor(s, 32);
      inv[qi] = 1.0f / s;
    }

    // write normalized P into qk buffer as pt[q][key] (Q/K now dead)
#pragma unroll
    for (int qi = 0; qi < 4; ++qi) {
      const int q = 16 * qi + c;
#pragma unroll
      for (int ki = 0; ki < 4; ++ki) {
        unsigned u0 = pkbf2(sa[ki][qi][0] * inv[qi], sa[ki][qi][1] * inv[qi]);
        unsigned u1 = pkbf2(sa[ki][qi][2] * inv[qi], sa[ki][qi][3] * inv[qi]);
        const int idx = (q * 64 + 16 * ki + 4 * g) ^ c7s;   // q&7 == c&7
        *(uint2*)&wl[idx] = make_uint2(u0, u1);
      }
    }

    // O = P @ V : A = pt rows, B = vt rows
    f32x4 oa[4][2];
#pragma unroll
    for (int mi = 0; mi < 4; ++mi)
#pragma unroll
      for (int nd = 0; nd < 2; ++nd) oa[mi][nd] = f32x4{0.f, 0.f, 0.f, 0.f};
#pragma unroll
    for (int ks2 = 0; ks2 < 2; ++ks2) {
      s16x8 pa[4], vb[2];
#pragma unroll
      for (int mi = 0; mi < 4; ++mi) {
        const int q = 16 * mi + c;
        pa[mi] = *(const s16x8*)&wl[(q * 64 + ks2 * 32 + 8 * g) ^ c7s];
      }
#pragma unroll
      for (int nd = 0; nd < 2; ++nd) {
        const int d = 16 * nd + c;
        vb[nd] = *(const s16x8*)&vtl[(d * 64 + ks2 * 32 + 8 * g) ^ c7s];
      }
#pragma unroll
      for (int mi = 0; mi < 4; ++mi)
#pragma unroll
        for (int nd = 0; nd < 2; ++nd)
          oa[mi][nd] = __builtin_amdgcn_mfma_f32_16x16x32_bf16(pa[mi], vb[nd], oa[mi][nd], 0, 0, 0);
    }
    // keep O packed in registers: (q = 16mi+4g+r, d = 16nd+c)
#pragma unroll
    for (int mi = 0; mi < 4; ++mi)
#pragma unroll
      for (int nd = 0; nd < 2; ++nd) {
        obp[p][mi][nd][0] = pkbf2(oa[mi][nd][0], oa[mi][nd][1]);
        obp[p][mi][nd][1] = pkbf2(oa[mi][nd][2], oa[mi][nd][3]);
      }
  } // pass loop

  __syncthreads();

  // scatter O into att[row][feat] (feat = h*32 + d), swizzled, overlapping dead regions
#pragma unroll
  for (int p = 0; p < 2; ++p) {
    const int h = 4 * p + w;
#pragma unroll
    for (int mi = 0; mi < 4; ++mi)
#pragma unroll
      for (int nd = 0; nd < 2; ++nd)
#pragma unroll
        for (int r = 0; r < 4; ++r) {
          const int q = 16 * mi + 4 * g + r;
          const int feat = h * 32 + 16 * nd + c;
          unsigned val = obp[p][mi][nd][r >> 1] >> (16 * (r & 1));
          lds[(q * 256 + feat) ^ ((q & 7) << 3)] = (unsigned short)val;
        }
  }
  __syncthreads();

  // ---------------- Phase C: out^T = Wproj @ att^T ----------------
  f32x4 pacc[4][4];
#pragma unroll
  for (int ti = 0; ti < 4; ++ti)
#pragma unroll
    for (int nj = 0; nj < 4; ++nj) pacc[ti][nj] = f32x4{0.f, 0.f, 0.f, 0.f};

#pragma unroll
  for (int ks = 0; ks < 8; ++ks) {
    const int kof = ks * 32 + 8 * g;
    s16x8 bx[4];
#pragma unroll
    for (int nj = 0; nj < 4; ++nj) {
      const int row = 16 * nj + c;
      bx[nj] = *(const s16x8*)&lds[(row * 256 + kof) ^ c7s];  // row&7 == c&7
    }
#pragma unroll
    for (int ti = 0; ti < 4; ++ti) {
      const int e = (4 * w + ti) * 16 + c;
      s16x8 aw = load_cvt8(wproj + (size_t)e * DM + kof);
#pragma unroll
      for (int nj = 0; nj < 4; ++nj)
        pacc[ti][nj] = __builtin_amdgcn_mfma_f32_16x16x32_bf16(aw, bx[nj], pacc[ti][nj], 0, 0, 0);
    }
  }

  // epilogue: bias + coalesced float4 stores. value = (e=(4w+ti)*16+4g+r, row=16nj+c)
  float* __restrict__ ob = out + (size_t)bn * (S_LEN * DM);
#pragma unroll
  for (int ti = 0; ti < 4; ++ti) {
    f32x4 bp = *(const f32x4*)(bproj + (4 * w + ti) * 16 + 4 * g);
#pragma unroll
    for (int nj = 0; nj < 4; ++nj) {
      const int row = 16 * nj + c;
      f32x4 v;
      v[0] = pacc[ti][nj][0] + bp[0];
      v[1] = pacc[ti][nj][1] + bp[1];
      v[2] = pacc[ti][nj][2] + bp[2];
      v[3] = pacc[ti][nj][3] + bp[3];
      *(f32x4*)(ob + (size_t)row * DM + (4 * w + ti) * 16 + 4 * g) = v;
    }
  }
}

extern "C" void kernel_launch(void* const* d_in, const int* in_sizes, int n_in,
                              void* d_out, int out_size, void* d_ws, size_t ws_size,
                              hipStream_t stream) {
  (void)n_in; (void)d_ws; (void)ws_size; (void)out_size;
  const float* x     = (const float*)d_in[0];
  const float* wqkv  = (const float*)d_in[1];
  const float* bqkv  = (const float*)d_in[2];
  const float* wproj = (const float*)d_in[3];
  const float* bproj = (const float*)d_in[4];
  float* out = (float*)d_out;

  const int bn_total = in_sizes[0] / (S_LEN * DM);  // 2600
  dim3 grid(bn_total), block(256);
  hipLaunchKernelGGL(ta_fused_kernel, grid, block, 0, stream,
                     x, wqkv, bqkv, wproj, bproj, out, bn_total);
}

// Round 2
// 310.301 us; speedup vs baseline: 2.3808x; 2.3808x over previous
//
#include <hip/hip_runtime.h>
#include <hip/hip_bf16.h>

// TemporalAttention fused kernel for MI355X (gfx950), round 2.
// - Weights pre-converted to bf16 in d_ws (prep kernel).
// - X staged once per block into LDS as bf16 (cooperative, swizzled).
// - One block per (b,n) sequence: 256 threads = 4 waves, each wave 2 heads.
// - All GEMMs transposed (W @ X^T); bf16 MFMA 16x16x32, f32 accumulation.
// - Output staged in LDS f32, stored as contiguous 1KB/wave rows.

namespace {

constexpr int S_LEN = 64;
constexpr int DM    = 256;
constexpr int NQKV  = 3 * DM * DM;   // 196608 f32 in w_qkv

typedef float f32x4 __attribute__((ext_vector_type(4)));
typedef short s16x8 __attribute__((ext_vector_type(8)));

union BF2 { __hip_bfloat162 h; unsigned u; };
__device__ __forceinline__ unsigned pkbf2(float a, float b) {
  float2 t; t.x = a; t.y = b;
  BF2 cv; cv.h = __float22bfloat162_rn(t);
  return cv.u;
}

union BF1 { __hip_bfloat16 h; unsigned short u; };
__device__ __forceinline__ unsigned short f2bf(float a) {
  BF1 cv; cv.h = __float2bfloat16(a); return cv.u;
}

} // namespace

// ---- prep: f32 weights -> bf16 in workspace ----
__global__ void ta_prep_weights(const float* __restrict__ wqkv,
                                const float* __restrict__ wproj,
                                unsigned short* __restrict__ wsb) {
  const int i = (blockIdx.x * 256 + (int)threadIdx.x) * 4;  // f32 index
  f32x4 v = (i < NQKV) ? *(const f32x4*)(wqkv + i)
                       : *(const f32x4*)(wproj + (i - NQKV));
  unsigned u0 = pkbf2(v[0], v[1]);
  unsigned u1 = pkbf2(v[2], v[3]);
  *(uint2*)(wsb + i) = make_uint2(u0, u1);
}

__global__ void __launch_bounds__(256, 2)
ta_fused_kernel(const float* __restrict__ x,
                const unsigned short* __restrict__ wq_bf,   // [768][256] bf16
                const float* __restrict__ bqkv,
                const unsigned short* __restrict__ wp_bf,   // [256][256] bf16
                const float* __restrict__ bproj,
                float* __restrict__ out, int bn_total)
{
  // LDS 80KB (40960 shorts):
  //   [0,16384)        : xls[64][256] bf16 (X staged, swizzled); later att[64][256]
  //   [16384 + w*6144) : per-wave qk[64][64] (4096) + vt[32][64] (2048)
  //   final epilogue   : ldsf[64][256] f32 (64KB) overlapping everything (dead)
  __shared__ __align__(16) unsigned short lds[40960];

  const int bn = blockIdx.x;
  if (bn >= bn_total) return;
  const int tid = (int)threadIdx.x;
  const int w = tid >> 6;
  const int l = tid & 63;
  const int g = l >> 4;
  const int c = l & 15;
  const int c7s = (c & 7) << 3;

  const float* __restrict__ xb = x + (size_t)bn * (S_LEN * DM);
  unsigned short* __restrict__ xls = lds;                 // also att after barrier
  unsigned short* __restrict__ wl  = lds + 16384 + w * 6144;
  unsigned short* __restrict__ vtl = wl + 4096;

  // ---- cooperative stage X -> LDS bf16 (swizzled) ----
#pragma unroll
  for (int it = 0; it < 8; ++it) {
    const int e = (it * 256 + tid) * 8;       // element index, 8-aligned
    const int row = e >> 8;
    f32x4 a = *(const f32x4*)(xb + e);
    f32x4 b = *(const f32x4*)(xb + e + 4);
    union { s16x8 v; unsigned u[4]; } r;
    r.u[0] = pkbf2(a[0], a[1]); r.u[1] = pkbf2(a[2], a[3]);
    r.u[2] = pkbf2(b[0], b[1]); r.u[3] = pkbf2(b[2], b[3]);
    *(s16x8*)&xls[e ^ ((row & 7) << 3)] = r.v;
  }
  __syncthreads();

  unsigned obp[2][4][2][2];  // packed bf16 attention output

#pragma unroll
  for (int p = 0; p < 2; ++p) {
    const int h = 4 * p + w;
    const int t0 = 2 * h;

    // ---------------- Phase A: QKV^T = Wqkv @ X^T for head h ----------------
    f32x4 acc[6][4];
#pragma unroll
    for (int mi = 0; mi < 6; ++mi)
#pragma unroll
      for (int nj = 0; nj < 4; ++nj) acc[mi][nj] = f32x4{0.f, 0.f, 0.f, 0.f};

#pragma unroll
    for (int ks = 0; ks < 8; ++ks) {
      const int kof = ks * 32 + g * 8;
      s16x8 bx[4];
#pragma unroll
      for (int nj = 0; nj < 4; ++nj) {
        const int row = 16 * nj + c;
        bx[nj] = *(const s16x8*)&xls[(row * 256 + kof) ^ c7s];  // row&7 == c&7
      }
#pragma unroll
      for (int mi = 0; mi < 6; ++mi) {
        const int tile = t0 + (mi & 1) + (mi >> 1) * 16;
        s16x8 aw = *(const s16x8*)&wq_bf[(size_t)(tile * 16 + c) * DM + kof];
#pragma unroll
        for (int nj = 0; nj < 4; ++nj)
          acc[mi][nj] = __builtin_amdgcn_mfma_f32_16x16x32_bf16(aw, bx[nj], acc[mi][nj], 0, 0, 0);
      }
    }

    // epilogue: bias; Q,K -> qk buffer; V -> vt (transposed)
#pragma unroll
    for (int mi = 0; mi < 6; ++mi) {
      const int tile = t0 + (mi & 1) + (mi >> 1) * 16;
      f32x4 bq = *(const f32x4*)(bqkv + tile * 16 + 4 * g);
      if (mi < 4) {
        const int colb = mi * 16 + 4 * g;
#pragma unroll
        for (int nj = 0; nj < 4; ++nj) {
          const int row = 16 * nj + c;
          unsigned u0 = pkbf2(acc[mi][nj][0] + bq[0], acc[mi][nj][1] + bq[1]);
          unsigned u1 = pkbf2(acc[mi][nj][2] + bq[2], acc[mi][nj][3] + bq[3]);
          *(uint2*)&wl[(row * 64 + colb) ^ c7s] = make_uint2(u0, u1);
        }
      } else {
#pragma unroll
        for (int nj = 0; nj < 4; ++nj) {
          const int key = 16 * nj + c;
#pragma unroll
          for (int r = 0; r < 4; ++r) {
            const int d = (mi - 4) * 16 + 4 * g + r;
            vtl[(d * 64 + key) ^ ((d & 7) << 3)] = f2bf(acc[mi][nj][r] + bq[r]);
          }
        }
      }
    }

    // ---------------- Phase B: attention ----------------
    s16x8 ka[4], qa[4];
#pragma unroll
    for (int ki = 0; ki < 4; ++ki) {
      const int key = 16 * ki + c;
      ka[ki] = *(const s16x8*)&wl[(key * 64 + 32 + 8 * g) ^ c7s];
    }
#pragma unroll
    for (int qi = 0; qi < 4; ++qi) {
      const int q = 16 * qi + c;
      qa[qi] = *(const s16x8*)&wl[(q * 64 + 8 * g) ^ c7s];
    }
    f32x4 sa[4][4];
#pragma unroll
    for (int ki = 0; ki < 4; ++ki)
#pragma unroll
      for (int qi = 0; qi < 4; ++qi) {
        f32x4 z = f32x4{0.f, 0.f, 0.f, 0.f};
        sa[ki][qi] = __builtin_amdgcn_mfma_f32_16x16x32_bf16(ka[ki], qa[qi], z, 0, 0, 0);
      }

    const float sc = 0.17677669529663687f * 1.4426950408889634f;
    float inv[4];
#pragma unroll
    for (int qi = 0; qi < 4; ++qi) {
      float m = sa[0][qi][0];
#pragma unroll
      for (int ki = 0; ki < 4; ++ki)
#pragma unroll
        for (int r = 0; r < 4; ++r) m = fmaxf(m, sa[ki][qi][r]);
      m = fmaxf(m, __shfl_xor(m, 16));
      m = fmaxf(m, __shfl_xor(m, 32));
      float s = 0.0f;
#pragma unroll
      for (int ki = 0; ki < 4; ++ki)
#pragma unroll
        for (int r = 0; r < 4; ++r) {
          float pv = exp2f((sa[ki][qi][r] - m) * sc);
          sa[ki][qi][r] = pv;
          s += pv;
        }
      s += __shfl_xor(s, 16);
      s += __shfl_xor(s, 32);
      inv[qi] = 1.0f / s;
    }

#pragma unroll
    for (int qi = 0; qi < 4; ++qi) {
      const int q = 16 * qi + c;
#pragma unroll
      for (int ki = 0; ki < 4; ++ki) {
        unsigned u0 = pkbf2(sa[ki][qi][0] * inv[qi], sa[ki][qi][1] * inv[qi]);
        unsigned u1 = pkbf2(sa[ki][qi][2] * inv[qi], sa[ki][qi][3] * inv[qi]);
        *(uint2*)&wl[(q * 64 + 16 * ki + 4 * g) ^ c7s] = make_uint2(u0, u1);
      }
    }

    f32x4 oa[4][2];
#pragma unroll
    for (int mi = 0; mi < 4; ++mi)
#pragma unroll
      for (int nd = 0; nd < 2; ++nd) oa[mi][nd] = f32x4{0.f, 0.f, 0.f, 0.f};
#pragma unroll
    for (int ks2 = 0; ks2 < 2; ++ks2) {
      s16x8 pa[4], vb[2];
#pragma unroll
      for (int mi = 0; mi < 4; ++mi) {
        const int q = 16 * mi + c;
        pa[mi] = *(const s16x8*)&wl[(q * 64 + ks2 * 32 + 8 * g) ^ c7s];
      }
#pragma unroll
      for (int nd = 0; nd < 2; ++nd) {
        const int d = 16 * nd + c;
        vb[nd] = *(const s16x8*)&vtl[(d * 64 + ks2 * 32 + 8 * g) ^ c7s];
      }
#pragma unroll
      for (int mi = 0; mi < 4; ++mi)
#pragma unroll
        for (int nd = 0; nd < 2; ++nd)
          oa[mi][nd] = __builtin_amdgcn_mfma_f32_16x16x32_bf16(pa[mi], vb[nd], oa[mi][nd], 0, 0, 0);
    }
#pragma unroll
    for (int mi = 0; mi < 4; ++mi)
#pragma unroll
      for (int nd = 0; nd < 2; ++nd) {
        obp[p][mi][nd][0] = pkbf2(oa[mi][nd][0], oa[mi][nd][1]);
        obp[p][mi][nd][1] = pkbf2(oa[mi][nd][2], oa[mi][nd][3]);
      }
  } // pass loop

  __syncthreads();  // all waves done with xls + their buffers

  // scatter O into att[row][feat] over the xls region
#pragma unroll
  for (int p = 0; p < 2; ++p) {
    const int h = 4 * p + w;
#pragma unroll
    for (int mi = 0; mi < 4; ++mi)
#pragma unroll
      for (int nd = 0; nd < 2; ++nd)
#pragma unroll
        for (int r = 0; r < 4; ++r) {
          const int q = 16 * mi + 4 * g + r;
          const int feat = h * 32 + 16 * nd + c;
          unsigned val = obp[p][mi][nd][r >> 1] >> (16 * (r & 1));
          lds[(q * 256 + feat) ^ ((q & 7) << 3)] = (unsigned short)val;
        }
  }
  __syncthreads();

  // ---------------- Phase C: out^T = Wproj @ att^T ----------------
  f32x4 pacc[4][4];
#pragma unroll
  for (int ti = 0; ti < 4; ++ti)
#pragma unroll
    for (int nj = 0; nj < 4; ++nj) pacc[ti][nj] = f32x4{0.f, 0.f, 0.f, 0.f};

#pragma unroll
  for (int ks = 0; ks < 8; ++ks) {
    const int kof = ks * 32 + 8 * g;
    s16x8 bx[4];
#pragma unroll
    for (int nj = 0; nj < 4; ++nj) {
      const int row = 16 * nj + c;
      bx[nj] = *(const s16x8*)&lds[(row * 256 + kof) ^ c7s];
    }
#pragma unroll
    for (int ti = 0; ti < 4; ++ti) {
      const int e = (4 * w + ti) * 16 + c;
      s16x8 aw = *(const s16x8*)&wp_bf[(size_t)e * DM + kof];
#pragma unroll
      for (int nj = 0; nj < 4; ++nj)
        pacc[ti][nj] = __builtin_amdgcn_mfma_f32_16x16x32_bf16(aw, bx[nj], pacc[ti][nj], 0, 0, 0);
    }
  }

  __syncthreads();  // att reads done; LDS reused as f32 out tile

  // stage out tile in LDS f32 (swizzled), then coalesced row stores
  float* ldsf = (float*)lds;
#pragma unroll
  for (int ti = 0; ti < 4; ++ti) {
    f32x4 bp = *(const f32x4*)(bproj + (4 * w + ti) * 16 + 4 * g);
#pragma unroll
    for (int nj = 0; nj < 4; ++nj) {
      const int row = 16 * nj + c;
      const int e0 = (4 * w + ti) * 16 + 4 * g;
      f32x4 v;
      v[0] = pacc[ti][nj][0] + bp[0];
      v[1] = pacc[ti][nj][1] + bp[1];
      v[2] = pacc[ti][nj][2] + bp[2];
      v[3] = pacc[ti][nj][3] + bp[3];
      *(f32x4*)&ldsf[(row * 256 + e0) ^ ((row & 7) << 2)] = v;
    }
  }
  __syncthreads();

  float* __restrict__ ob = out + (size_t)bn * (S_LEN * DM);
#pragma unroll
  for (int it = 0; it < 16; ++it) {
    const int i = (it * 256 + tid) * 4;   // f32 index, coalesced
    const int row = i >> 8;
    f32x4 v = *(const f32x4*)&ldsf[i ^ ((row & 7) << 2)];
    *(f32x4*)(ob + i) = v;
  }
}

extern "C" void kernel_launch(void* const* d_in, const int* in_sizes, int n_in,
                              void* d_out, int out_size, void* d_ws, size_t ws_size,
                              hipStream_t stream) {
  (void)n_in; (void)ws_size; (void)out_size;
  const float* x     = (const float*)d_in[0];
  const float* wqkv  = (const float*)d_in[1];
  const float* bqkv  = (const float*)d_in[2];
  const float* wproj = (const float*)d_in[3];
  const float* bproj = (const float*)d_in[4];
  float* out = (float*)d_out;

  unsigned short* wsb = (unsigned short*)d_ws;          // [768*256] qkv + [256*256] proj
  const unsigned short* wq_bf = wsb;
  const unsigned short* wp_bf = wsb + NQKV;

  // prep: 262144 f32 total, 4 per thread, 256 threads -> 256 blocks
  hipLaunchKernelGGL(ta_prep_weights, dim3(256), dim3(256), 0, stream, wqkv, wproj, wsb);

  const int bn_total = in_sizes[0] / (S_LEN * DM);      // 2600
  hipLaunchKernelGGL(ta_fused_kernel, dim3(bn_total), dim3(256), 0, stream,
                     x, wq_bf, bqkv, wp_bf, bproj, out, bn_total);
}